// Round 12
// baseline (1055.690 us; speedup 1.0000x reference)
//
#include <hip/hip_runtime.h>
#include <hip/hip_bf16.h>

// Problem constants
#define PN 16384
#define PZ 100
#define PE 400
#define PM0 4000
#define PM1 2000
#define KP 128            // packed K: [0,100)=theta/topic, [100,104)=onehot/bias, rest 0
#define SEG1ROW 4096      // B2T row base of segment 1
#define MROWS 6144        // 4096 (seg0 pad) + 2048 (seg1 pad)

typedef __attribute__((ext_vector_type(8))) _Float16 half8v;
typedef __attribute__((ext_vector_type(4))) float floatx4;
typedef __attribute__((ext_vector_type(4))) unsigned int uint4v;

// ---------------------------------------------------------------------------
// zero-fill whole B2T (pads + k-slop deterministically zero)
// ---------------------------------------------------------------------------
__global__ __launch_bounds__(256) void fill_kernel(uint4v* __restrict__ p, int n16)
{
    int i = blockIdx.x * 256 + threadIdx.x;
    if (i < n16) p[i] = (uint4v){0u, 0u, 0u, 0u};
}

// ---------------------------------------------------------------------------
// topic v5 (unchanged): grid (96,5); block = 64 m x 20 z; thread = 1 m x 5 z.
// alpha AND beta staged in LDS; e in 4 chunks of 100.
// ---------------------------------------------------------------------------
__global__ __launch_bounds__(256) void topic_kernel(
    const float* __restrict__ alpha0, const float* __restrict__ alpha1,
    const float* __restrict__ beta, _Float16* __restrict__ b2t)
{
    __shared__ float sAl[64][101];   // 25.9 KB
    __shared__ float sBt[20][100];   // 8 KB

    const int seg = (blockIdx.x >= 64);
    const int tile = seg ? (blockIdx.x - 64) : blockIdx.x;
    const float* alpha = seg ? alpha1 : alpha0;
    const int Mse = seg ? PM1 : PM0;
    const int rowbase = (seg ? SEG1ROW : 0) + tile * 64;
    const int m0 = tile * 64;

    const int tid = threadIdx.x;
    const int ml = tid & 63;
    const int zt = tid >> 6;              // wave id 0..3
    const int z0 = blockIdx.y * 20;       // block z-base

    float acc[5] = {0.f, 0.f, 0.f, 0.f, 0.f};

    for (int ec = 0; ec < 4; ++ec) {
        #pragma unroll
        for (int l = 0; l < 25; ++l) {
            int idx = tid + l * 256;
            int mr = idx / 100;
            int e  = idx - mr * 100;
            int mm = m0 + mr;
            sAl[mr][e] = (mm < Mse) ? alpha[(size_t)mm * PE + ec * 100 + e] : 0.f;
        }
        for (int idx = tid; idx < 2000; idx += 256) {
            int zr = idx / 100;
            int e  = idx - zr * 100;
            sBt[zr][e] = beta[(size_t)(z0 + zr) * PE + ec * 100 + e];
        }
        __syncthreads();

        #pragma unroll 2
        for (int e = 0; e < 100; ++e) {
            float a = sAl[ml][e];
            #pragma unroll
            for (int zi = 0; zi < 5; ++zi)
                acc[zi] = fmaf(sBt[zt * 5 + zi][e], a, acc[zi]);
        }
        __syncthreads();
    }

    int m = m0 + ml;
    if (m < Mse) {
        #pragma unroll
        for (int zi = 0; zi < 5; ++zi)
            b2t[(size_t)(rowbase + ml) * KP + (z0 + zt * 5 + zi)] = (_Float16)acc[zi];
    }
}

// ---------------------------------------------------------------------------
// bias cols k=100..103 of B2T (one thread per row)
// ---------------------------------------------------------------------------
__global__ __launch_bounds__(256) void bias_kernel(
    const float* __restrict__ bias0, const float* __restrict__ bias1,
    _Float16* __restrict__ b2t)
{
    int row = blockIdx.x * 256 + threadIdx.x;
    if (row >= MROWS) return;
    int seg = (row >= SEG1ROW);
    int m = row - (seg ? SEG1ROW : 0);
    int Mse = seg ? PM1 : PM0;
    const float* bias = seg ? bias1 : bias0;
    if (m < Mse) {
        #pragma unroll
        for (int d = 0; d < 4; ++d)
            b2t[(size_t)row * KP + 100 + d] = (_Float16)bias[(size_t)d * Mse + m];
    }
}

// ---------------------------------------------------------------------------
// Fused GEMM + LSE + writeout, v5: one SEGMENT per block (seg in blockIdx
// parity) -> grid 1024 = 4 blocks/CU at VGPR<=64, doubling occupancy vs v4.
// Block = 512 threads (8 waves) x 32 rows x one segment.
// ---------------------------------------------------------------------------
__global__ __launch_bounds__(512, 8) void fused_kernel(
    const float* __restrict__ theta,
    const _Float16* __restrict__ B2T,
    const int* __restrict__ dom,
    float* __restrict__ out0, float* __restrict__ out1)
{
    __shared__ __align__(1024) char sA[32 * 256];   // 8 KB swizzled A panel
    __shared__ float smx[8][32];
    __shared__ float sms[8][32];
    __shared__ float slse[32];

    const int tid = threadIdx.x;
    const int w   = tid >> 6;     // 0..7
    const int ll  = tid & 63;
    const int g   = ll >> 4;      // 0..3
    const int c   = ll & 15;      // 0..15

    const int seg = blockIdx.x & 1;
    const int n0  = (blockIdx.x >> 1) * 32;
    const int Mse = seg ? PM1 : PM0;
    const int NT  = seg ? 16 : 32;                 // 128-col tiles (even)
    const _Float16* Bseg = B2T + (size_t)(seg ? SEG1ROW : 0) * KP;
    float* out = seg ? out1 : out0;

    // ---- stage A: theta f32 -> f16 + one-hot domain at k=100..103 ----
    {
        int row  = tid >> 4;          // 0..31
        int slot = tid & 15;
        const float* tr = theta + (size_t)(n0 + row) * PZ + slot * 8;
        half8v h = (half8v)(_Float16)0.f;
        if (slot < 12) {
            float4 lo = *(const float4*)tr;
            float4 hi = *(const float4*)(tr + 4);
            h[0] = (_Float16)lo.x; h[1] = (_Float16)lo.y;
            h[2] = (_Float16)lo.z; h[3] = (_Float16)lo.w;
            h[4] = (_Float16)hi.x; h[5] = (_Float16)hi.y;
            h[6] = (_Float16)hi.z; h[7] = (_Float16)hi.w;
        } else if (slot == 12) {
            float4 lo = *(const float4*)tr;   // k = 96..99
            h[0] = (_Float16)lo.x; h[1] = (_Float16)lo.y;
            h[2] = (_Float16)lo.z; h[3] = (_Float16)lo.w;
            int d = dom[n0 + row];            // k=100..103: one-hot(dom)
            h[4] = (_Float16)(d == 0 ? 1.f : 0.f);
            h[5] = (_Float16)(d == 1 ? 1.f : 0.f);
            h[6] = (_Float16)(d == 2 ? 1.f : 0.f);
            h[7] = (_Float16)(d == 3 ? 1.f : 0.f);
        }
        *(half8v*)(sA + row * 256 + ((slot ^ (row & 7)) * 16)) = h;
    }
    __syncthreads();

    // ---- A fragments -> registers ----
    half8v aF[2][4];
    #pragma unroll
    for (int mi = 0; mi < 2; ++mi) {
        int row = mi * 16 + c;
        #pragma unroll
        for (int kb = 0; kb < 4; ++kb) {
            int slot = (kb * 4 + g) ^ (row & 7);
            aF[mi][kb] = *(const half8v*)(sA + row * 256 + slot * 16);
        }
    }

    const int mbase = w * 16 + c;
    const _Float16* bp0 = Bseg + (size_t)mbase * KP;   // lane's B row
    const size_t TSTEP = (size_t)128 * KP;

    float mx_[2][4], sm_[2][4];
    #pragma unroll
    for (int mi = 0; mi < 2; ++mi)
        #pragma unroll
        for (int i = 0; i < 4; ++i) { mx_[mi][i] = -3.0e38f; sm_[mi][i] = 0.f; }

    // ---- helpers ----
    auto loadB = [&](half8v (&bf)[4], const _Float16* p) {
        #pragma unroll
        for (int kb = 0; kb < 4; ++kb)
            bf[kb] = *(const half8v*)(p + kb * 32 + g * 8);
    };
    auto mfma8 = [&](half8v (&bf)[4], floatx4& a0, floatx4& a1) {
        a0 = (floatx4){0.f, 0.f, 0.f, 0.f};
        a1 = (floatx4){0.f, 0.f, 0.f, 0.f};
        #pragma unroll
        for (int kb = 0; kb < 4; ++kb) {
            a0 = __builtin_amdgcn_mfma_f32_16x16x32_f16(aF[0][kb], bf[kb], a0, 0, 0, 0);
            a1 = __builtin_amdgcn_mfma_f32_16x16x32_f16(aF[1][kb], bf[kb], a1, 0, 0, 0);
        }
    };
    auto stats_step = [&](floatx4& a0, floatx4& a1, int t) {
        const bool mv = (t * 128 + mbase) < Mse;
        float vv[2][4];
        float gm = -3.0e38f;
        #pragma unroll
        for (int mi = 0; mi < 2; ++mi)
            #pragma unroll
            for (int i = 0; i < 4; ++i) {
                float v = mv ? (mi ? a1[i] : a0[i]) : -1.0e30f;
                vv[mi][i] = v;
                gm = fmaxf(gm, v - mx_[mi][i]);
            }
        if (gm <= 8.0f) {
            #pragma unroll
            for (int mi = 0; mi < 2; ++mi)
                #pragma unroll
                for (int i = 0; i < 4; ++i)
                    sm_[mi][i] += __expf(vv[mi][i] - mx_[mi][i]);
        } else {
            #pragma unroll
            for (int mi = 0; mi < 2; ++mi)
                #pragma unroll
                for (int i = 0; i < 4; ++i) {
                    float v  = vv[mi][i];
                    float nm = fmaxf(mx_[mi][i], v);
                    sm_[mi][i] = sm_[mi][i] * __expf(mx_[mi][i] - nm) + __expf(v - nm);
                    mx_[mi][i] = nm;
                }
        }
    };

    // =========== stats sweep, x2-unrolled prefetch ===========
    {
        half8v bA[4], bB[4];
        floatx4 a0, a1;
        const _Float16* bp = bp0;
        loadB(bA, bp);
        for (int t = 0; t < NT; t += 2) {
            loadB(bB, bp + TSTEP);
            mfma8(bA, a0, a1);
            stats_step(a0, a1, t);
            if (t + 2 < NT) loadB(bA, bp + 2 * TSTEP);
            mfma8(bB, a0, a1);
            stats_step(a0, a1, t + 1);
            bp += 2 * TSTEP;
        }
    }

    // =========== reduce -> per-row LSE ===========
    #pragma unroll
    for (int mi = 0; mi < 2; ++mi) {
        #pragma unroll
        for (int i = 0; i < 4; ++i) {
            float m_ = mx_[mi][i], s_ = sm_[mi][i];
            #pragma unroll
            for (int msk = 1; msk < 16; msk <<= 1) {
                float mo = __shfl_xor(m_, msk);
                float so = __shfl_xor(s_, msk);
                float nm = fmaxf(m_, mo);
                s_ = s_ * __expf(m_ - nm) + so * __expf(mo - nm);
                m_ = nm;
            }
            if (c == 0) {
                int row = mi * 16 + 4 * g + i;
                smx[w][row] = m_;
                sms[w][row] = s_;
            }
        }
    }
    __syncthreads();
    if (tid < 32) {
        float m_ = smx[0][tid], s_ = sms[0][tid];
        #pragma unroll
        for (int wv = 1; wv < 8; ++wv) {
            float mo = smx[wv][tid];
            float so = sms[wv][tid];
            float nm = fmaxf(m_, mo);
            s_ = s_ * __expf(m_ - nm) + so * __expf(mo - nm);
            m_ = nm;
        }
        slse[tid] = m_ + __logf(s_);
    }
    __syncthreads();
    float lse_[2][4];
    #pragma unroll
    for (int mi = 0; mi < 2; ++mi)
        #pragma unroll
        for (int i = 0; i < 4; ++i)
            lse_[mi][i] = slse[mi * 16 + 4 * g + i];

    // =========== write sweep (recompute), x2-unrolled prefetch ===========
    {
        float* op[2][4];
        #pragma unroll
        for (int mi = 0; mi < 2; ++mi)
            #pragma unroll
            for (int i = 0; i < 4; ++i)
                op[mi][i] = out + (size_t)(n0 + mi * 16 + 4 * g + i) * Mse + mbase;

        auto write_step = [&](floatx4& a0, floatx4& a1, int t) {
            const bool mv = (t * 128 + mbase) < Mse;
            if (mv) {
                #pragma unroll
                for (int mi = 0; mi < 2; ++mi)
                    #pragma unroll
                    for (int i = 0; i < 4; ++i) {
                        float o = (mi ? a1[i] : a0[i]) - lse_[mi][i];
                        __builtin_nontemporal_store(o, op[mi][i]);
                    }
            }
            #pragma unroll
            for (int mi = 0; mi < 2; ++mi)
                #pragma unroll
                for (int i = 0; i < 4; ++i)
                    op[mi][i] += 128;
        };

        half8v bA[4], bB[4];
        floatx4 a0, a1;
        const _Float16* bp = bp0;
        loadB(bA, bp);
        for (int t = 0; t < NT; t += 2) {
            loadB(bB, bp + TSTEP);
            mfma8(bA, a0, a1);
            write_step(a0, a1, t);
            if (t + 2 < NT) loadB(bA, bp + 2 * TSTEP);
            mfma8(bB, a0, a1);
            write_step(a0, a1, t + 1);
            bp += 2 * TSTEP;
        }
    }
}

// ---------------------------------------------------------------------------
extern "C" void kernel_launch(void* const* d_in, const int* in_sizes, int n_in,
                              void* d_out, int out_size, void* d_ws, size_t ws_size,
                              hipStream_t stream) {
    const float* theta  = (const float*)d_in[0];
    const float* alpha0 = (const float*)d_in[1];
    const float* alpha1 = (const float*)d_in[2];
    const float* beta   = (const float*)d_in[3];
    const float* bias0  = (const float*)d_in[4];
    const float* bias1  = (const float*)d_in[5];
    const int*   dom    = (const int*)d_in[6];

    float* out0 = (float*)d_out;
    float* out1 = out0 + (size_t)PN * PM0;

    _Float16* B2T = (_Float16*)d_ws;   // [MROWS][KP] f16, 1.57 MB

    // 1. zero B2T (pads + unused k deterministically zero)
    {
        int n16 = MROWS * KP * 2 / 16;
        fill_kernel<<<(n16 + 255) / 256, 256, 0, stream>>>((uint4v*)B2T, n16);
    }

    // 2. topics -> B2T k=0..99
    topic_kernel<<<dim3(96, 5), 256, 0, stream>>>(alpha0, alpha1, beta, B2T);

    // 3. bias cols k=100..103
    bias_kernel<<<MROWS / 256, 256, 0, stream>>>(bias0, bias1, B2T);

    // 4. fused GEMM(+bias) + LSE + writeout: 1024 blocks (seg x row-panel)
    fused_kernel<<<(PN / 32) * 2, 512, 0, stream>>>(theta, B2T, dom, out0, out1);
}

// Round 13
// 307.144 us; speedup vs baseline: 3.4371x; 3.4371x over previous
//
#include <hip/hip_runtime.h>
#include <hip/hip_bf16.h>

// Problem constants
#define PN 16384
#define PZ 100
#define PE 400
#define PM0 4000
#define PM1 2000
#define KP 128            // packed K: [0,100)=theta/topic, [100,104)=onehot/bias, rest 0
#define SEG1ROW 4096      // B2T row base of segment 1
#define MROWS 6144        // 4096 (seg0 pad) + 2048 (seg1 pad)

typedef __attribute__((ext_vector_type(8))) _Float16 half8v;
typedef __attribute__((ext_vector_type(4))) float floatx4;
typedef __attribute__((ext_vector_type(4))) unsigned int uint4v;

// ---------------------------------------------------------------------------
// zero-fill whole B2T (pads + k-slop deterministically zero)
// ---------------------------------------------------------------------------
__global__ __launch_bounds__(256) void fill_kernel(uint4v* __restrict__ p, int n16)
{
    int i = blockIdx.x * 256 + threadIdx.x;
    if (i < n16) p[i] = (uint4v){0u, 0u, 0u, 0u};
}

// ---------------------------------------------------------------------------
// topic v5 (unchanged): grid (96,5); block = 64 m x 20 z; thread = 1 m x 5 z.
// alpha AND beta staged in LDS; e in 4 chunks of 100.
// ---------------------------------------------------------------------------
__global__ __launch_bounds__(256) void topic_kernel(
    const float* __restrict__ alpha0, const float* __restrict__ alpha1,
    const float* __restrict__ beta, _Float16* __restrict__ b2t)
{
    __shared__ float sAl[64][101];   // 25.9 KB
    __shared__ float sBt[20][100];   // 8 KB

    const int seg = (blockIdx.x >= 64);
    const int tile = seg ? (blockIdx.x - 64) : blockIdx.x;
    const float* alpha = seg ? alpha1 : alpha0;
    const int Mse = seg ? PM1 : PM0;
    const int rowbase = (seg ? SEG1ROW : 0) + tile * 64;
    const int m0 = tile * 64;

    const int tid = threadIdx.x;
    const int ml = tid & 63;
    const int zt = tid >> 6;              // wave id 0..3
    const int z0 = blockIdx.y * 20;       // block z-base

    float acc[5] = {0.f, 0.f, 0.f, 0.f, 0.f};

    for (int ec = 0; ec < 4; ++ec) {
        #pragma unroll
        for (int l = 0; l < 25; ++l) {
            int idx = tid + l * 256;
            int mr = idx / 100;
            int e  = idx - mr * 100;
            int mm = m0 + mr;
            sAl[mr][e] = (mm < Mse) ? alpha[(size_t)mm * PE + ec * 100 + e] : 0.f;
        }
        for (int idx = tid; idx < 2000; idx += 256) {
            int zr = idx / 100;
            int e  = idx - zr * 100;
            sBt[zr][e] = beta[(size_t)(z0 + zr) * PE + ec * 100 + e];
        }
        __syncthreads();

        #pragma unroll 2
        for (int e = 0; e < 100; ++e) {
            float a = sAl[ml][e];
            #pragma unroll
            for (int zi = 0; zi < 5; ++zi)
                acc[zi] = fmaf(sBt[zt * 5 + zi][e], a, acc[zi]);
        }
        __syncthreads();
    }

    int m = m0 + ml;
    if (m < Mse) {
        #pragma unroll
        for (int zi = 0; zi < 5; ++zi)
            b2t[(size_t)(rowbase + ml) * KP + (z0 + zt * 5 + zi)] = (_Float16)acc[zi];
    }
}

// ---------------------------------------------------------------------------
// bias cols k=100..103 of B2T (one thread per row)
// ---------------------------------------------------------------------------
__global__ __launch_bounds__(256) void bias_kernel(
    const float* __restrict__ bias0, const float* __restrict__ bias1,
    _Float16* __restrict__ b2t)
{
    int row = blockIdx.x * 256 + threadIdx.x;
    if (row >= MROWS) return;
    int seg = (row >= SEG1ROW);
    int m = row - (seg ? SEG1ROW : 0);
    int Mse = seg ? PM1 : PM0;
    const float* bias = seg ? bias1 : bias0;
    if (m < Mse) {
        #pragma unroll
        for (int d = 0; d < 4; ++d)
            b2t[(size_t)row * KP + 100 + d] = (_Float16)bias[(size_t)d * Mse + m];
    }
}

// ---------------------------------------------------------------------------
// Fused GEMM + LSE + writeout, v6 = v5 grid (1024 blocks, one segment per
// block via blockIdx parity) + v4 launch bounds (512,4): VGPR=64, no spill.
// VGPR=64 permits 8 waves/SIMD -> the 1024-block grid fills 4 blocks/CU.
// ---------------------------------------------------------------------------
__global__ __launch_bounds__(512, 4) void fused_kernel(
    const float* __restrict__ theta,
    const _Float16* __restrict__ B2T,
    const int* __restrict__ dom,
    float* __restrict__ out0, float* __restrict__ out1)
{
    __shared__ __align__(1024) char sA[32 * 256];   // 8 KB swizzled A panel
    __shared__ float smx[8][32];
    __shared__ float sms[8][32];
    __shared__ float slse[32];

    const int tid = threadIdx.x;
    const int w   = tid >> 6;     // 0..7
    const int ll  = tid & 63;
    const int g   = ll >> 4;      // 0..3
    const int c   = ll & 15;      // 0..15

    const int seg = blockIdx.x & 1;
    const int n0  = (blockIdx.x >> 1) * 32;
    const int Mse = seg ? PM1 : PM0;
    const int NT  = seg ? 16 : 32;                 // 128-col tiles (even)
    const _Float16* Bseg = B2T + (size_t)(seg ? SEG1ROW : 0) * KP;
    float* out = seg ? out1 : out0;

    // ---- stage A: theta f32 -> f16 + one-hot domain at k=100..103 ----
    {
        int row  = tid >> 4;          // 0..31
        int slot = tid & 15;
        const float* tr = theta + (size_t)(n0 + row) * PZ + slot * 8;
        half8v h = (half8v)(_Float16)0.f;
        if (slot < 12) {
            float4 lo = *(const float4*)tr;
            float4 hi = *(const float4*)(tr + 4);
            h[0] = (_Float16)lo.x; h[1] = (_Float16)lo.y;
            h[2] = (_Float16)lo.z; h[3] = (_Float16)lo.w;
            h[4] = (_Float16)hi.x; h[5] = (_Float16)hi.y;
            h[6] = (_Float16)hi.z; h[7] = (_Float16)hi.w;
        } else if (slot == 12) {
            float4 lo = *(const float4*)tr;   // k = 96..99
            h[0] = (_Float16)lo.x; h[1] = (_Float16)lo.y;
            h[2] = (_Float16)lo.z; h[3] = (_Float16)lo.w;
            int d = dom[n0 + row];            // k=100..103: one-hot(dom)
            h[4] = (_Float16)(d == 0 ? 1.f : 0.f);
            h[5] = (_Float16)(d == 1 ? 1.f : 0.f);
            h[6] = (_Float16)(d == 2 ? 1.f : 0.f);
            h[7] = (_Float16)(d == 3 ? 1.f : 0.f);
        }
        *(half8v*)(sA + row * 256 + ((slot ^ (row & 7)) * 16)) = h;
    }
    __syncthreads();

    // ---- A fragments -> registers ----
    half8v aF[2][4];
    #pragma unroll
    for (int mi = 0; mi < 2; ++mi) {
        int row = mi * 16 + c;
        #pragma unroll
        for (int kb = 0; kb < 4; ++kb) {
            int slot = (kb * 4 + g) ^ (row & 7);
            aF[mi][kb] = *(const half8v*)(sA + row * 256 + slot * 16);
        }
    }

    const int mbase = w * 16 + c;
    const _Float16* bp0 = Bseg + (size_t)mbase * KP;   // lane's B row
    const size_t TSTEP = (size_t)128 * KP;

    float mx_[2][4], sm_[2][4];
    #pragma unroll
    for (int mi = 0; mi < 2; ++mi)
        #pragma unroll
        for (int i = 0; i < 4; ++i) { mx_[mi][i] = -3.0e38f; sm_[mi][i] = 0.f; }

    // ---- helpers ----
    auto loadB = [&](half8v (&bf)[4], const _Float16* p) {
        #pragma unroll
        for (int kb = 0; kb < 4; ++kb)
            bf[kb] = *(const half8v*)(p + kb * 32 + g * 8);
    };
    auto mfma8 = [&](half8v (&bf)[4], floatx4& a0, floatx4& a1) {
        a0 = (floatx4){0.f, 0.f, 0.f, 0.f};
        a1 = (floatx4){0.f, 0.f, 0.f, 0.f};
        #pragma unroll
        for (int kb = 0; kb < 4; ++kb) {
            a0 = __builtin_amdgcn_mfma_f32_16x16x32_f16(aF[0][kb], bf[kb], a0, 0, 0, 0);
            a1 = __builtin_amdgcn_mfma_f32_16x16x32_f16(aF[1][kb], bf[kb], a1, 0, 0, 0);
        }
    };
    auto stats_step = [&](floatx4& a0, floatx4& a1, int t) {
        const bool mv = (t * 128 + mbase) < Mse;
        float vv[2][4];
        float gm = -3.0e38f;
        #pragma unroll
        for (int mi = 0; mi < 2; ++mi)
            #pragma unroll
            for (int i = 0; i < 4; ++i) {
                float v = mv ? (mi ? a1[i] : a0[i]) : -1.0e30f;
                vv[mi][i] = v;
                gm = fmaxf(gm, v - mx_[mi][i]);
            }
        if (gm <= 8.0f) {
            #pragma unroll
            for (int mi = 0; mi < 2; ++mi)
                #pragma unroll
                for (int i = 0; i < 4; ++i)
                    sm_[mi][i] += __expf(vv[mi][i] - mx_[mi][i]);
        } else {
            #pragma unroll
            for (int mi = 0; mi < 2; ++mi)
                #pragma unroll
                for (int i = 0; i < 4; ++i) {
                    float v  = vv[mi][i];
                    float nm = fmaxf(mx_[mi][i], v);
                    sm_[mi][i] = sm_[mi][i] * __expf(mx_[mi][i] - nm) + __expf(v - nm);
                    mx_[mi][i] = nm;
                }
        }
    };

    // =========== stats sweep, x2-unrolled prefetch ===========
    {
        half8v bA[4], bB[4];
        floatx4 a0, a1;
        const _Float16* bp = bp0;
        loadB(bA, bp);
        for (int t = 0; t < NT; t += 2) {
            loadB(bB, bp + TSTEP);
            mfma8(bA, a0, a1);
            stats_step(a0, a1, t);
            if (t + 2 < NT) loadB(bA, bp + 2 * TSTEP);
            mfma8(bB, a0, a1);
            stats_step(a0, a1, t + 1);
            bp += 2 * TSTEP;
        }
    }

    // =========== reduce -> per-row LSE ===========
    #pragma unroll
    for (int mi = 0; mi < 2; ++mi) {
        #pragma unroll
        for (int i = 0; i < 4; ++i) {
            float m_ = mx_[mi][i], s_ = sm_[mi][i];
            #pragma unroll
            for (int msk = 1; msk < 16; msk <<= 1) {
                float mo = __shfl_xor(m_, msk);
                float so = __shfl_xor(s_, msk);
                float nm = fmaxf(m_, mo);
                s_ = s_ * __expf(m_ - nm) + so * __expf(mo - nm);
                m_ = nm;
            }
            if (c == 0) {
                int row = mi * 16 + 4 * g + i;
                smx[w][row] = m_;
                sms[w][row] = s_;
            }
        }
    }
    __syncthreads();
    if (tid < 32) {
        float m_ = smx[0][tid], s_ = sms[0][tid];
        #pragma unroll
        for (int wv = 1; wv < 8; ++wv) {
            float mo = smx[wv][tid];
            float so = sms[wv][tid];
            float nm = fmaxf(m_, mo);
            s_ = s_ * __expf(m_ - nm) + so * __expf(mo - nm);
            m_ = nm;
        }
        slse[tid] = m_ + __logf(s_);
    }
    __syncthreads();
    float lse_[2][4];
    #pragma unroll
    for (int mi = 0; mi < 2; ++mi)
        #pragma unroll
        for (int i = 0; i < 4; ++i)
            lse_[mi][i] = slse[mi * 16 + 4 * g + i];

    // =========== write sweep (recompute), x2-unrolled prefetch ===========
    {
        float* op[2][4];
        #pragma unroll
        for (int mi = 0; mi < 2; ++mi)
            #pragma unroll
            for (int i = 0; i < 4; ++i)
                op[mi][i] = out + (size_t)(n0 + mi * 16 + 4 * g + i) * Mse + mbase;

        auto write_step = [&](floatx4& a0, floatx4& a1, int t) {
            const bool mv = (t * 128 + mbase) < Mse;
            if (mv) {
                #pragma unroll
                for (int mi = 0; mi < 2; ++mi)
                    #pragma unroll
                    for (int i = 0; i < 4; ++i) {
                        float o = (mi ? a1[i] : a0[i]) - lse_[mi][i];
                        __builtin_nontemporal_store(o, op[mi][i]);
                    }
            }
            #pragma unroll
            for (int mi = 0; mi < 2; ++mi)
                #pragma unroll
                for (int i = 0; i < 4; ++i)
                    op[mi][i] += 128;
        };

        half8v bA[4], bB[4];
        floatx4 a0, a1;
        const _Float16* bp = bp0;
        loadB(bA, bp);
        for (int t = 0; t < NT; t += 2) {
            loadB(bB, bp + TSTEP);
            mfma8(bA, a0, a1);
            write_step(a0, a1, t);
            if (t + 2 < NT) loadB(bA, bp + 2 * TSTEP);
            mfma8(bB, a0, a1);
            write_step(a0, a1, t + 1);
            bp += 2 * TSTEP;
        }
    }
}

// ---------------------------------------------------------------------------
extern "C" void kernel_launch(void* const* d_in, const int* in_sizes, int n_in,
                              void* d_out, int out_size, void* d_ws, size_t ws_size,
                              hipStream_t stream) {
    const float* theta  = (const float*)d_in[0];
    const float* alpha0 = (const float*)d_in[1];
    const float* alpha1 = (const float*)d_in[2];
    const float* beta   = (const float*)d_in[3];
    const float* bias0  = (const float*)d_in[4];
    const float* bias1  = (const float*)d_in[5];
    const int*   dom    = (const int*)d_in[6];

    float* out0 = (float*)d_out;
    float* out1 = out0 + (size_t)PN * PM0;

    _Float16* B2T = (_Float16*)d_ws;   // [MROWS][KP] f16, 1.57 MB

    // 1. zero B2T (pads + unused k deterministically zero)
    {
        int n16 = MROWS * KP * 2 / 16;
        fill_kernel<<<(n16 + 255) / 256, 256, 0, stream>>>((uint4v*)B2T, n16);
    }

    // 2. topics -> B2T k=0..99
    topic_kernel<<<dim3(96, 5), 256, 0, stream>>>(alpha0, alpha1, beta, B2T);

    // 3. bias cols k=100..103
    bias_kernel<<<MROWS / 256, 256, 0, stream>>>(bias0, bias1, B2T);

    // 4. fused GEMM(+bias) + LSE + writeout: 1024 blocks (seg x row-panel)
    fused_kernel<<<(PN / 32) * 2, 512, 0, stream>>>(theta, B2T, dom, out0, out1);
}

// Round 14
// 269.631 us; speedup vs baseline: 3.9153x; 1.1391x over previous
//
#include <hip/hip_runtime.h>
#include <hip/hip_bf16.h>

// Problem constants
#define PN 16384
#define PZ 100
#define PE 400
#define PM0 4000
#define PM1 2000
#define KP 128            // packed K: [0,100)=theta/topic, [100,104)=onehot/bias, rest 0
#define SEG1ROW 4096      // B2T row base of segment 1
#define MROWS 6144        // 4096 (seg0 pad) + 2048 (seg1 pad)

typedef __attribute__((ext_vector_type(8))) _Float16 half8v;
typedef __attribute__((ext_vector_type(4))) float floatx4;
typedef __attribute__((ext_vector_type(4))) unsigned int uint4v;

// ---------------------------------------------------------------------------
// zero-fill whole B2T (pads + k-slop deterministically zero)
// ---------------------------------------------------------------------------
__global__ __launch_bounds__(256) void fill_kernel(uint4v* __restrict__ p, int n16)
{
    int i = blockIdx.x * 256 + threadIdx.x;
    if (i < n16) p[i] = (uint4v){0u, 0u, 0u, 0u};
}

// ---------------------------------------------------------------------------
// topic v5 (unchanged): grid (96,5); block = 64 m x 20 z; thread = 1 m x 5 z.
// ---------------------------------------------------------------------------
__global__ __launch_bounds__(256) void topic_kernel(
    const float* __restrict__ alpha0, const float* __restrict__ alpha1,
    const float* __restrict__ beta, _Float16* __restrict__ b2t)
{
    __shared__ float sAl[64][101];   // 25.9 KB
    __shared__ float sBt[20][100];   // 8 KB

    const int seg = (blockIdx.x >= 64);
    const int tile = seg ? (blockIdx.x - 64) : blockIdx.x;
    const float* alpha = seg ? alpha1 : alpha0;
    const int Mse = seg ? PM1 : PM0;
    const int rowbase = (seg ? SEG1ROW : 0) + tile * 64;
    const int m0 = tile * 64;

    const int tid = threadIdx.x;
    const int ml = tid & 63;
    const int zt = tid >> 6;
    const int z0 = blockIdx.y * 20;

    float acc[5] = {0.f, 0.f, 0.f, 0.f, 0.f};

    for (int ec = 0; ec < 4; ++ec) {
        #pragma unroll
        for (int l = 0; l < 25; ++l) {
            int idx = tid + l * 256;
            int mr = idx / 100;
            int e  = idx - mr * 100;
            int mm = m0 + mr;
            sAl[mr][e] = (mm < Mse) ? alpha[(size_t)mm * PE + ec * 100 + e] : 0.f;
        }
        for (int idx = tid; idx < 2000; idx += 256) {
            int zr = idx / 100;
            int e  = idx - zr * 100;
            sBt[zr][e] = beta[(size_t)(z0 + zr) * PE + ec * 100 + e];
        }
        __syncthreads();

        #pragma unroll 2
        for (int e = 0; e < 100; ++e) {
            float a = sAl[ml][e];
            #pragma unroll
            for (int zi = 0; zi < 5; ++zi)
                acc[zi] = fmaf(sBt[zt * 5 + zi][e], a, acc[zi]);
        }
        __syncthreads();
    }

    int m = m0 + ml;
    if (m < Mse) {
        #pragma unroll
        for (int zi = 0; zi < 5; ++zi)
            b2t[(size_t)(rowbase + ml) * KP + (z0 + zt * 5 + zi)] = (_Float16)acc[zi];
    }
}

// ---------------------------------------------------------------------------
// bias cols k=100..103 of B2T (one thread per row)
// ---------------------------------------------------------------------------
__global__ __launch_bounds__(256) void bias_kernel(
    const float* __restrict__ bias0, const float* __restrict__ bias1,
    _Float16* __restrict__ b2t)
{
    int row = blockIdx.x * 256 + threadIdx.x;
    if (row >= MROWS) return;
    int seg = (row >= SEG1ROW);
    int m = row - (seg ? SEG1ROW : 0);
    int Mse = seg ? PM1 : PM0;
    const float* bias = seg ? bias1 : bias0;
    if (m < Mse) {
        #pragma unroll
        for (int d = 0; d < 4; ++d)
            b2t[(size_t)row * KP + 100 + d] = (_Float16)bias[(size_t)d * Mse + m];
    }
}

// ---------------------------------------------------------------------------
// Fused GEMM + LSE + writeout, v7: v4's uniform 512-block grid (both segments
// serial per block) + SWAPPED MFMA operands (D transposed) so each lane holds
// 4 consecutive m-values -> 2 x float4 PLAIN stores per tile (L2 write-combine)
// instead of 8 scattered nontemporal dwords. Stats tracked per n (2 regs).
// ---------------------------------------------------------------------------
__global__ __launch_bounds__(512, 4) void fused_kernel(
    const float* __restrict__ theta,
    const _Float16* __restrict__ B2T,
    const int* __restrict__ dom,
    float* __restrict__ out0, float* __restrict__ out1)
{
    __shared__ __align__(1024) char sA[32 * 256];   // 8 KB swizzled A panel
    __shared__ float smx[8][32];
    __shared__ float sms[8][32];
    __shared__ float slse[32];

    const int tid = threadIdx.x;
    const int w   = tid >> 6;     // 0..7
    const int ll  = tid & 63;
    const int g   = ll >> 4;      // 0..3
    const int c   = ll & 15;      // 0..15
    const int n0  = blockIdx.x * 32;

    // ---- stage A: theta f32 -> f16 + one-hot domain at k=100..103 ----
    {
        int row  = tid >> 4;          // 0..31
        int slot = tid & 15;
        const float* tr = theta + (size_t)(n0 + row) * PZ + slot * 8;
        half8v h = (half8v)(_Float16)0.f;
        if (slot < 12) {
            float4 lo = *(const float4*)tr;
            float4 hi = *(const float4*)(tr + 4);
            h[0] = (_Float16)lo.x; h[1] = (_Float16)lo.y;
            h[2] = (_Float16)lo.z; h[3] = (_Float16)lo.w;
            h[4] = (_Float16)hi.x; h[5] = (_Float16)hi.y;
            h[6] = (_Float16)hi.z; h[7] = (_Float16)hi.w;
        } else if (slot == 12) {
            float4 lo = *(const float4*)tr;   // k = 96..99
            h[0] = (_Float16)lo.x; h[1] = (_Float16)lo.y;
            h[2] = (_Float16)lo.z; h[3] = (_Float16)lo.w;
            int d = dom[n0 + row];            // k=100..103: one-hot(dom)
            h[4] = (_Float16)(d == 0 ? 1.f : 0.f);
            h[5] = (_Float16)(d == 1 ? 1.f : 0.f);
            h[6] = (_Float16)(d == 2 ? 1.f : 0.f);
            h[7] = (_Float16)(d == 3 ? 1.f : 0.f);
        }
        *(half8v*)(sA + row * 256 + ((slot ^ (row & 7)) * 16)) = h;
    }
    __syncthreads();

    // ---- A fragments -> registers (B-operand after swap) ----
    half8v aF[2][4];
    #pragma unroll
    for (int mi = 0; mi < 2; ++mi) {
        int row = mi * 16 + c;
        #pragma unroll
        for (int kb = 0; kb < 4; ++kb) {
            int slot = (kb * 4 + g) ^ (row & 7);
            aF[mi][kb] = *(const half8v*)(sA + row * 256 + slot * 16);
        }
    }

    const int mwave = w * 16 + 4 * g;     // lane's first m within a tile

    for (int seg = 0; seg < 2; ++seg) {
        const int Mse = seg ? PM1 : PM0;
        const int NT  = seg ? 16 : 32;    // 128-col tiles (even)
        const _Float16* Bseg = B2T + (size_t)(seg ? SEG1ROW : 0) * KP;
        float* out = seg ? out1 : out0;

        const _Float16* bp0 = Bseg + (size_t)(w * 16 + c) * KP;  // lane's B row
        const size_t TSTEP = (size_t)128 * KP;

        float mx0 = -3.0e38f, mx1 = -3.0e38f, sm0 = 0.f, sm1 = 0.f;

        auto loadB = [&](half8v (&bf)[4], const _Float16* p) {
            #pragma unroll
            for (int kb = 0; kb < 4; ++kb)
                bf[kb] = *(const half8v*)(p + kb * 32 + g * 8);
        };
        // swapped: bF is the A-operand -> D rows = m, D cols = n
        auto mfma8 = [&](half8v (&bf)[4], floatx4& a0, floatx4& a1) {
            a0 = (floatx4){0.f, 0.f, 0.f, 0.f};
            a1 = (floatx4){0.f, 0.f, 0.f, 0.f};
            #pragma unroll
            for (int kb = 0; kb < 4; ++kb) {
                a0 = __builtin_amdgcn_mfma_f32_16x16x32_f16(bf[kb], aF[0][kb], a0, 0, 0, 0);
                a1 = __builtin_amdgcn_mfma_f32_16x16x32_f16(bf[kb], aF[1][kb], a1, 0, 0, 0);
            }
        };
        auto stats_step = [&](floatx4& a0, floatx4& a1, int t) {
            const bool mval = (t * 128 + mwave) < Mse;
            float v0[4], v1[4];
            #pragma unroll
            for (int i = 0; i < 4; ++i) {
                v0[i] = mval ? a0[i] : -1.0e30f;
                v1[i] = mval ? a1[i] : -1.0e30f;
            }
            float tm0 = fmaxf(fmaxf(v0[0], v0[1]), fmaxf(v0[2], v0[3]));
            float tm1 = fmaxf(fmaxf(v1[0], v1[1]), fmaxf(v1[2], v1[3]));
            float gm = fmaxf(tm0 - mx0, tm1 - mx1);
            if (__all(gm <= 8.0f)) {
                sm0 += __expf(v0[0] - mx0) + __expf(v0[1] - mx0)
                     + __expf(v0[2] - mx0) + __expf(v0[3] - mx0);
                sm1 += __expf(v1[0] - mx1) + __expf(v1[1] - mx1)
                     + __expf(v1[2] - mx1) + __expf(v1[3] - mx1);
            } else {
                float nm0 = fmaxf(mx0, tm0);
                float nm1 = fmaxf(mx1, tm1);
                sm0 = sm0 * __expf(mx0 - nm0)
                    + __expf(v0[0] - nm0) + __expf(v0[1] - nm0)
                    + __expf(v0[2] - nm0) + __expf(v0[3] - nm0);
                sm1 = sm1 * __expf(mx1 - nm1)
                    + __expf(v1[0] - nm1) + __expf(v1[1] - nm1)
                    + __expf(v1[2] - nm1) + __expf(v1[3] - nm1);
                mx0 = nm0; mx1 = nm1;
            }
        };

        // =========== stats sweep, x2-unrolled prefetch ===========
        {
            half8v bA[4], bB[4];
            floatx4 a0, a1;
            const _Float16* bp = bp0;
            loadB(bA, bp);
            for (int t = 0; t < NT; t += 2) {
                loadB(bB, bp + TSTEP);
                mfma8(bA, a0, a1);
                stats_step(a0, a1, t);
                if (t + 2 < NT) loadB(bA, bp + 2 * TSTEP);
                mfma8(bB, a0, a1);
                stats_step(a0, a1, t + 1);
                bp += 2 * TSTEP;
            }
        }

        // =========== reduce over g (masks 16,32) -> per-row LSE ===========
        {
            float m0 = mx0, s0 = sm0, m1 = mx1, s1 = sm1;
            #pragma unroll
            for (int msk = 16; msk <= 32; msk <<= 1) {
                float mo0 = __shfl_xor(m0, msk), so0 = __shfl_xor(s0, msk);
                float mo1 = __shfl_xor(m1, msk), so1 = __shfl_xor(s1, msk);
                float nm0 = fmaxf(m0, mo0);
                s0 = s0 * __expf(m0 - nm0) + so0 * __expf(mo0 - nm0);
                m0 = nm0;
                float nm1 = fmaxf(m1, mo1);
                s1 = s1 * __expf(m1 - nm1) + so1 * __expf(mo1 - nm1);
                m1 = nm1;
            }
            if (ll < 16) {
                smx[w][ll] = m0;      sms[w][ll] = s0;
                smx[w][16 + ll] = m1; sms[w][16 + ll] = s1;
            }
        }
        __syncthreads();
        if (tid < 32) {
            float m_ = smx[0][tid], s_ = sms[0][tid];
            #pragma unroll
            for (int wv = 1; wv < 8; ++wv) {
                float mo = smx[wv][tid];
                float so = sms[wv][tid];
                float nm = fmaxf(m_, mo);
                s_ = s_ * __expf(m_ - nm) + so * __expf(mo - nm);
                m_ = nm;
            }
            slse[tid] = m_ + __logf(s_);
        }
        __syncthreads();
        const float lse0 = slse[c];
        const float lse1 = slse[16 + c];

        // =========== write sweep (recompute), float4 plain stores ===========
        {
            float* p0 = out + (size_t)(n0 + c) * Mse + mwave;
            float* p1 = out + (size_t)(n0 + 16 + c) * Mse + mwave;

            auto write_step = [&](floatx4& a0, floatx4& a1, int t) {
                if ((t * 128 + mwave) < Mse) {
                    floatx4 o0 = {a0[0] - lse0, a0[1] - lse0, a0[2] - lse0, a0[3] - lse0};
                    floatx4 o1 = {a1[0] - lse1, a1[1] - lse1, a1[2] - lse1, a1[3] - lse1};
                    *(floatx4*)p0 = o0;
                    *(floatx4*)p1 = o1;
                }
                p0 += 128;
                p1 += 128;
            };

            half8v bA[4], bB[4];
            floatx4 a0, a1;
            const _Float16* bp = bp0;
            loadB(bA, bp);
            for (int t = 0; t < NT; t += 2) {
                loadB(bB, bp + TSTEP);
                mfma8(bA, a0, a1);
                write_step(a0, a1, t);
                if (t + 2 < NT) loadB(bA, bp + 2 * TSTEP);
                mfma8(bB, a0, a1);
                write_step(a0, a1, t + 1);
                bp += 2 * TSTEP;
            }
        }
    }
}

// ---------------------------------------------------------------------------
extern "C" void kernel_launch(void* const* d_in, const int* in_sizes, int n_in,
                              void* d_out, int out_size, void* d_ws, size_t ws_size,
                              hipStream_t stream) {
    const float* theta  = (const float*)d_in[0];
    const float* alpha0 = (const float*)d_in[1];
    const float* alpha1 = (const float*)d_in[2];
    const float* beta   = (const float*)d_in[3];
    const float* bias0  = (const float*)d_in[4];
    const float* bias1  = (const float*)d_in[5];
    const int*   dom    = (const int*)d_in[6];

    float* out0 = (float*)d_out;
    float* out1 = out0 + (size_t)PN * PM0;

    _Float16* B2T = (_Float16*)d_ws;   // [MROWS][KP] f16, 1.57 MB

    // 1. zero B2T (pads + unused k deterministically zero)
    {
        int n16 = MROWS * KP * 2 / 16;
        fill_kernel<<<(n16 + 255) / 256, 256, 0, stream>>>((uint4v*)B2T, n16);
    }

    // 2. topics -> B2T k=0..99
    topic_kernel<<<dim3(96, 5), 256, 0, stream>>>(alpha0, alpha1, beta, B2T);

    // 3. bias cols k=100..103
    bias_kernel<<<MROWS / 256, 256, 0, stream>>>(bias0, bias1, B2T);

    // 4. fused GEMM(+bias) + LSE + writeout: uniform 512 blocks, both segs
    fused_kernel<<<PN / 32, 512, 0, stream>>>(theta, B2T, dom, out0, out1);
}